// Round 7
// baseline (185.844 us; speedup 1.0000x reference)
//
#include <hip/hip_runtime.h>
#include <hip/hip_bf16.h>

#define BB 8
#define TT 2048
#define CC 1024
#define HH 64
#define NTRI 528                 // 32*33/2 triangular 64x64 tiles per batch
#define NPB (TT * HH)            // 131072 elems per batch per tensor

typedef unsigned short ushort_t;
typedef __attribute__((ext_vector_type(8))) short bf16x8;
typedef __attribute__((ext_vector_type(4))) float f32x4;

__device__ __forceinline__ float bf2f(ushort_t u) {
    unsigned int x = ((unsigned int)u) << 16;
    return __uint_as_float(x);
}
__device__ __forceinline__ ushort_t f2bf(float f) {
    unsigned int x = __float_as_uint(f);
    unsigned int lsb = (x >> 16) & 1;
    x += 0x7fffu + lsb;   // round-to-nearest-even
    return (ushort_t)(x >> 16);
}

// ---------------------------------------------------------------------------
// Kernel 0: pack weights into MFMA B-fragment records.
// wpack[part(5)][kc(32)][nt(4)][lane(64)][8]; parts: qh,ql,kh,kl,vh.
// record elem j (lane=(quad,l15)): W[c=kc*32+quad*8+j][h=nt*16+l15]
// ---------------------------------------------------------------------------
__global__ __launch_bounds__(256) void wsplit_kernel(
    const float* __restrict__ Wq, const float* __restrict__ Wk,
    const float* __restrict__ Wv, ushort_t* __restrict__ wpack)
{
    int slot = blockIdx.x * 256 + threadIdx.x;   // [0, 40960)
    int rec = slot >> 6, lane = slot & 63;
    int quad = lane >> 4, l15 = lane & 15;
    int part = rec >> 7;
    int r2 = rec & 127;
    int kc = r2 >> 2, nt = r2 & 3;
    const float* W = (part < 2) ? Wq : (part < 4) ? Wk : Wv;
    bool lo = (part < 4) && (part & 1);
    bf16x8 o;
    #pragma unroll
    for (int j = 0; j < 8; j++) {
        int c = kc * 32 + quad * 8 + j;
        float w = W[(size_t)c * HH + nt * 16 + l15];
        ushort_t h = f2bf(w);
        o[j] = (short)(lo ? f2bf(w - bf2f(h)) : h);
    }
    *(bf16x8*)(wpack + (size_t)rec * 512 + lane * 8) = o;
}

// ---------------------------------------------------------------------------
// Kernel 1: fused q/k/v projection. Grid 1024, block = 16 M rows.
// Wave = one n-tile (wid). Barrier-free K-loop: direct-from-global A-frags
// (2 float4 per kc, 1-deep prefetch), coalesced weight records. Small LDS
// epilogue emits packed q/k (hi/lo) + v records.
// ---------------------------------------------------------------------------
__global__ __launch_bounds__(256) void proj_mfma(
    const float* __restrict__ x, const ushort_t* __restrict__ wpack,
    ushort_t* __restrict__ qpk, ushort_t* __restrict__ qpl,
    ushort_t* __restrict__ kpk, ushort_t* __restrict__ kpl,
    ushort_t* __restrict__ vpk)
{
    const int tid = threadIdx.x;
    const int lane = tid & 63, wid = tid >> 6;
    const int quad = lane >> 4, l15 = lane & 15;
    const int r0 = blockIdx.x * 16;
    const int nt = wid;

    __shared__ __align__(16) float sC[3 * 16 * 72];   // 13.8 KB

    f32x4 accQ = {0.f, 0.f, 0.f, 0.f};
    f32x4 accK = {0.f, 0.f, 0.f, 0.f};
    f32x4 accV = {0.f, 0.f, 0.f, 0.f};

    const float* xrow = x + (size_t)(r0 + l15) * CC + quad * 8;
    const ushort_t* wbase = wpack + (size_t)nt * 512 + (size_t)lane * 8;

    float4 c0 = *(const float4*)(xrow);
    float4 c1 = *(const float4*)(xrow + 4);

    for (int kc = 0; kc < 32; kc++) {
        // convert current x chunk to split bf16
        float xv[8] = {c0.x, c0.y, c0.z, c0.w, c1.x, c1.y, c1.z, c1.w};
        bf16x8 aH, aL;
        #pragma unroll
        for (int j = 0; j < 8; j++) {
            ushort_t h = f2bf(xv[j]);
            aH[j] = (short)h;
            aL[j] = (short)f2bf(xv[j] - bf2f(h));
        }
        // prefetch next chunk (overlaps weight loads + MFMAs)
        if (kc < 31) {
            c0 = *(const float4*)(xrow + (kc + 1) * 32);
            c1 = *(const float4*)(xrow + (kc + 1) * 32 + 4);
        }
        const ushort_t* wk = wbase + (size_t)kc * 2048;
        bf16x8 bQh = *(const bf16x8*)(wk);
        bf16x8 bQl = *(const bf16x8*)(wk + 65536);
        bf16x8 bKh = *(const bf16x8*)(wk + 2 * 65536);
        bf16x8 bKl = *(const bf16x8*)(wk + 3 * 65536);
        bf16x8 bVh = *(const bf16x8*)(wk + 4 * 65536);
        accQ = __builtin_amdgcn_mfma_f32_16x16x32_bf16(aL, bQh, accQ, 0, 0, 0);
        accQ = __builtin_amdgcn_mfma_f32_16x16x32_bf16(aH, bQl, accQ, 0, 0, 0);
        accQ = __builtin_amdgcn_mfma_f32_16x16x32_bf16(aH, bQh, accQ, 0, 0, 0);
        accK = __builtin_amdgcn_mfma_f32_16x16x32_bf16(aL, bKh, accK, 0, 0, 0);
        accK = __builtin_amdgcn_mfma_f32_16x16x32_bf16(aH, bKl, accK, 0, 0, 0);
        accK = __builtin_amdgcn_mfma_f32_16x16x32_bf16(aH, bKh, accK, 0, 0, 0);
        accV = __builtin_amdgcn_mfma_f32_16x16x32_bf16(aH, bVh, accV, 0, 0, 0);
    }

    // dump C tiles: sC[p][row(16)][72], row = quad*4+r, col = nt*16+l15
    #pragma unroll
    for (int r = 0; r < 4; r++) {
        sC[(0 * 16 + quad * 4 + r) * 72 + nt * 16 + l15] = accQ[r];
        sC[(1 * 16 + quad * 4 + r) * 72 + nt * 16 + l15] = accK[r];
        sC[(2 * 16 + quad * 4 + r) * 72 + nt * 16 + l15] = accV[r];
    }
    __syncthreads();

    const int b = r0 >> 11;
    const int gt = (r0 & 2047) >> 4;

    // q,k: rec = (pp, ks); elem j = C[pp][l15][ks*32+quad*8+j], split hi/lo
    {
        const int rec = tid >> 6;
        const int pp = rec >> 1, ks = rec & 1;
        const float* src = &sC[(pp * 16 + l15) * 72 + ks * 32 + quad * 8];
        f32x4 v0 = *(const f32x4*)src;
        f32x4 v1 = *(const f32x4*)(src + 4);
        bf16x8 h8, l8;
        #pragma unroll
        for (int j = 0; j < 4; j++) {
            ushort_t h = f2bf(v0[j]);
            h8[j] = (short)h;
            l8[j] = (short)f2bf(v0[j] - bf2f(h));
        }
        #pragma unroll
        for (int j = 0; j < 4; j++) {
            ushort_t h = f2bf(v1[j]);
            h8[4 + j] = (short)h;
            l8[4 + j] = (short)f2bf(v1[j] - bf2f(h));
        }
        const size_t dst = (size_t)b * NPB + (((size_t)ks * 128 + gt) * 64 + lane) * 8;
        *(bf16x8*)((pp == 0 ? qpk : kpk) + dst) = h8;
        *(bf16x8*)((pp == 0 ? qpl : kpl) + dst) = l8;
    }
    // v: record (sc, nt); this block fills half a record (16 of 32 s-rows)
    {
        const int ntv = tid >> 6;
        const int sc = (r0 & 2047) >> 5;
        const int halfSel = (r0 >> 4) & 1;
        if ((quad >> 1) == halfSel) {
            bf16x8 o;
            #pragma unroll
            for (int j = 0; j < 8; j++)
                o[j] = (short)f2bf(sC[(2 * 16 + (quad & 1) * 8 + j) * 72 + ntv * 16 + l15]);
            *(bf16x8*)(vpk + (size_t)b * NPB + (((size_t)sc * 4 + ntv) * 64 + lane) * 8) = o;
        }
    }
}

// ---------------------------------------------------------------------------
// Kernel 2: l[b,s] += column sums of exp(qk^T); stores P = exp(S) bf16 in
// PV-A-fragment-packed triangular tiles. Block 128x128, wave 64x64.
// ---------------------------------------------------------------------------
__global__ __launch_bounds__(256) void colsum_mfma(
    const ushort_t* __restrict__ qpk, const ushort_t* __restrict__ qpl,
    const ushort_t* __restrict__ kpk, const ushort_t* __restrict__ kpl,
    float* __restrict__ lsum, ushort_t* __restrict__ Ppack)
{
    const int tc = blockIdx.x, st = blockIdx.y, b = blockIdx.z;
    if (tc < st) return;
    const int tid = threadIdx.x;
    const int lane = tid & 63, wid = tid >> 6;
    const int quad = lane >> 4, l15 = lane & 15;
    const int wy = wid >> 1, wx = wid & 1;
    const int t_base = tc * 128 + wy * 64;
    const int s_base = st * 128 + wx * 64;
    if (t_base < s_base) return;
    const bool needMask = (t_base == s_base);

    __shared__ __align__(16) ushort_t sT[4][64][72];   // 36.9 KB, wave-private

    const size_t bq = (size_t)b * NPB;
    const size_t lb8 = (size_t)lane * 8;

    bf16x8 bH[4][2], bL[4][2];
    #pragma unroll
    for (int nt = 0; nt < 4; nt++)
        #pragma unroll
        for (int ks = 0; ks < 2; ks++) {
            const size_t off = bq + (((size_t)ks * 128 + (s_base >> 4) + nt) * 64) * 8 + lb8;
            bH[nt][ks] = *(const bf16x8*)(kpk + off);
            bL[nt][ks] = *(const bf16x8*)(kpl + off);
        }

    float cs[4] = {0.f, 0.f, 0.f, 0.f};

    #pragma unroll
    for (int mt = 0; mt < 4; mt++) {
        bf16x8 aH[2], aL[2];
        #pragma unroll
        for (int ks = 0; ks < 2; ks++) {
            const size_t off = bq + (((size_t)ks * 128 + (t_base >> 4) + mt) * 64) * 8 + lb8;
            aH[ks] = *(const bf16x8*)(qpk + off);
            aL[ks] = *(const bf16x8*)(qpl + off);
        }
        f32x4 acc[4];
        #pragma unroll
        for (int nt = 0; nt < 4; nt++)
            acc[nt] = (f32x4){0.f, 0.f, 0.f, 0.f};
        #pragma unroll
        for (int nt = 0; nt < 4; nt++)
            #pragma unroll
            for (int ks = 0; ks < 2; ks++) {
                acc[nt] = __builtin_amdgcn_mfma_f32_16x16x32_bf16(aL[ks], bH[nt][ks], acc[nt], 0, 0, 0);
                acc[nt] = __builtin_amdgcn_mfma_f32_16x16x32_bf16(aH[ks], bL[nt][ks], acc[nt], 0, 0, 0);
                acc[nt] = __builtin_amdgcn_mfma_f32_16x16x32_bf16(aH[ks], bH[nt][ks], acc[nt], 0, 0, 0);
            }
        #pragma unroll
        for (int nt = 0; nt < 4; nt++)
            #pragma unroll
            for (int r = 0; r < 4; r++) {
                float e = __expf(acc[nt][r]);
                if (needMask) {
                    int t = mt * 16 + quad * 4 + r;
                    int s = nt * 16 + l15;
                    if (t < s) e = 0.f;
                }
                cs[nt] += e;
                sT[wid][mt * 16 + quad * 4 + r][nt * 16 + l15] = f2bf(e);
            }
    }

    #pragma unroll
    for (int nt = 0; nt < 4; nt++) {
        float v = cs[nt];
        v += __shfl_xor(v, 16);
        v += __shfl_xor(v, 32);
        if (quad == 0)
            atomicAdd(lsum + (size_t)b * TT + s_base + nt * 16 + l15, v);
    }

    const int ti = t_base >> 6, si = s_base >> 6;
    ushort_t* tp = Ppack + ((size_t)b * NTRI + (size_t)(ti * (ti + 1) / 2) + si) * 4096;
    #pragma unroll
    for (int rec = 0; rec < 8; rec++) {
        const int mtP = rec >> 1, ksP = rec & 1;
        bf16x8 v8 = *(const bf16x8*)&sT[wid][mtP * 16 + l15][ksP * 32 + quad * 8];
        *(bf16x8*)(tp + (size_t)rec * 512 + lb8) = v8;
    }
}

// ---------------------------------------------------------------------------
// Kernel 2b: scale packed v records by 1/l[s]  (s = sc*32 + quad*8 + j)
// ---------------------------------------------------------------------------
__global__ __launch_bounds__(256) void vscale_kernel(
    const ushort_t* __restrict__ vpk, const float* __restrict__ lsum,
    ushort_t* __restrict__ vps)
{
    size_t slot = (size_t)blockIdx.x * 256 + threadIdx.x;   // 131072 slots
    int lane = (int)(slot & 63);
    int quad = lane >> 4;
    int sc_b = (int)(slot >> 8);          // b*64 + sc
    int b = sc_b >> 6, sc = sc_b & 63;
    bf16x8 in = *(const bf16x8*)(vpk + slot * 8);
    const float* lp = lsum + (size_t)b * TT + sc * 32 + quad * 8;
    float4 l0 = *(const float4*)lp;
    float4 l1 = *(const float4*)(lp + 4);
    float li[8] = {l0.x, l0.y, l0.z, l0.w, l1.x, l1.y, l1.z, l1.w};
    bf16x8 o;
    #pragma unroll
    for (int j = 0; j < 8; j++)
        o[j] = (short)f2bf(bf2f((ushort_t)in[j]) / li[j]);
    *(bf16x8*)(vps + slot * 8) = o;
}

// ---------------------------------------------------------------------------
// Kernel 3: out = P * vs^T. grid (32, 8). Barrier-free: wave w owns m-tile
// (wid&1) of 32-row tile {p | w<2} / {63-p | w>=2}; full s-range; direct store.
// ---------------------------------------------------------------------------
__global__ __launch_bounds__(256) void attn_pv(
    const ushort_t* __restrict__ Ppack, const ushort_t* __restrict__ vps,
    float* __restrict__ out)
{
    const int p = blockIdx.x, b = blockIdx.y;
    const int tid = threadIdx.x;
    const int lane = tid & 63, wid = tid >> 6;
    const int quad = lane >> 4, l15 = lane & 15;
    const size_t lb8 = (size_t)lane * 8;

    const int tile32 = (wid >> 1) ? (63 - p) : p;
    const int gt = tile32 * 2 + (wid & 1);       // global 16-row tile [0,128)
    const int ti = gt >> 2, mtP = gt & 3;        // 64-tile, m-tile within

    const size_t triBase = ((size_t)b * NTRI + (size_t)(ti * (ti + 1) / 2)) * 4096;
    const ushort_t* vb_ = vps + (size_t)b * NPB;

    f32x4 acc[4];
    #pragma unroll
    for (int nt = 0; nt < 4; nt++)
        acc[nt] = (f32x4){0.f, 0.f, 0.f, 0.f};

    bf16x8 pa0 = *(const bf16x8*)(Ppack + triBase + (size_t)(mtP * 2 + 0) * 512 + lb8);
    bf16x8 pa1 = *(const bf16x8*)(Ppack + triBase + (size_t)(mtP * 2 + 1) * 512 + lb8);

    for (int si = 0; si <= ti; si++) {
        bf16x8 vb[2][4];
        #pragma unroll
        for (int ks = 0; ks < 2; ks++)
            #pragma unroll
            for (int nt = 0; nt < 4; nt++)
                vb[ks][nt] = *(const bf16x8*)(vb_ + (((size_t)(si * 2 + ks) * 4 + nt) * 512) + lb8);
        bf16x8 npa0, npa1;
        if (si < ti) {
            const ushort_t* ntp = Ppack + triBase + (size_t)(si + 1) * 4096;
            npa0 = *(const bf16x8*)(ntp + (size_t)(mtP * 2 + 0) * 512 + lb8);
            npa1 = *(const bf16x8*)(ntp + (size_t)(mtP * 2 + 1) * 512 + lb8);
        }
        #pragma unroll
        for (int nt = 0; nt < 4; nt++) {
            acc[nt] = __builtin_amdgcn_mfma_f32_16x16x32_bf16(pa0, vb[0][nt], acc[nt], 0, 0, 0);
            acc[nt] = __builtin_amdgcn_mfma_f32_16x16x32_bf16(pa1, vb[1][nt], acc[nt], 0, 0, 0);
        }
        pa0 = npa0; pa1 = npa1;
    }

    #pragma unroll
    for (int nt = 0; nt < 4; nt++)
        #pragma unroll
        for (int r = 0; r < 4; r++)
            out[(size_t)(b * TT + gt * 16 + quad * 4 + r) * HH + nt * 16 + l15] = acc[nt][r];
}

extern "C" void kernel_launch(void* const* d_in, const int* in_sizes, int n_in,
                              void* d_out, int out_size, void* d_ws, size_t ws_size,
                              hipStream_t stream)
{
    const float* x  = (const float*)d_in[0];
    const float* Wq = (const float*)d_in[1];
    const float* Wk = (const float*)d_in[2];
    const float* Wv = (const float*)d_in[3];
    float* out = (float*)d_out;

    const size_t N = (size_t)BB * TT * HH;     // 1,048,576
    ushort_t* qpk = (ushort_t*)d_ws;
    ushort_t* qpl = qpk + N;
    ushort_t* kpk = qpl + N;
    ushort_t* kpl = kpk + N;
    ushort_t* vpk = kpl + N;
    ushort_t* vps = vpk + N;
    float* lsum = (float*)(vps + N);                        // [8][2048]
    ushort_t* wpack = (ushort_t*)(lsum + (size_t)BB * TT);  // 327,680 elems
    ushort_t* Ppack = wpack + (size_t)5 * 32 * 4 * 512;     // 17,301,504 elems

    hipMemsetAsync(lsum, 0, (size_t)BB * TT * sizeof(float), stream);
    wsplit_kernel<<<dim3(160), 256, 0, stream>>>(Wq, Wk, Wv, wpack);
    proj_mfma<<<dim3(1024), 256, 0, stream>>>(x, wpack, qpk, qpl, kpk, kpl, vpk);
    colsum_mfma<<<dim3(16, 16, BB), 256, 0, stream>>>(qpk, qpl, kpk, kpl, lsum, Ppack);
    vscale_kernel<<<dim3(512), 256, 0, stream>>>(vpk, lsum, vps);
    attn_pv<<<dim3(32, BB), 256, 0, stream>>>(Ppack, vps, out);
}